// Round 1
// baseline (327.266 us; speedup 1.0000x reference)
//
#include <hip/hip_runtime.h>

// GraphSAGE 2-layer forward on MI355X.
// Round 11: XCD-resident layer-2 aggregation. r10 counters: agg2_add is the
// top dispatch (44.5us), FETCH 98MB = 2.2TB/s of L2-miss traffic gathering
// from an 8MB t2 table that exceeds the 4MB per-XCD L2. Now t2 is split into
// TWO 20-dim bf16 tables (4.0MB each); the agg2 grid is doubled and swizzled
// so XCDs 0-3 gather only t2a and XCDs 4-7 only t2b (blockIdx%8 round-robin
// heuristic). Streaming accesses (csr_src, out RMW) use nontemporal hints so
// they don't evict the resident table. Per-lane in-flight bytes halve but
// wave count doubles -> aggregate MLP preserved (r9 lesson).
//   agg_mean: unchanged (fp8 rows, 16 lanes/edge, 4 gathers/lane).
// CSR: deterministic counting sort. GEMM: fused gemm12 (h1 tile in LDS).

typedef __attribute__((ext_vector_type(8))) short bf16x8;
typedef __attribute__((ext_vector_type(4))) float f32x4;
typedef __attribute__((ext_vector_type(2))) float f32x2;

#define BIN_SHIFT 7
#define BIN_SIZE  128
#define NB        256          // scatter blocks (= scan block size!)

#define OFF_ROWSTART (1ull << 20)   // 400 KB
#define OFF_HIST     (2ull << 20)   // 800 KB  hist[bin*NB + blk]
#define OFF_SCAN     (3ull << 20)   // 800 KB  block-local exclusive prefix
#define OFF_BSUMS    (4ull << 20)
#define OFF_BOFFS    ((4ull << 20) + (64ull << 10))
#define OFF_PACKED   (5ull << 20)   // 6.4 MB
#define OFF_CSR      (12ull << 20)  // 6.4 MB
#define OFF_W1T      (19ull << 20)  // 64 KB
#define OFF_W2T      (20ull << 20)  // 20 KB
#define OFF_XB       (21ull << 20)  // 25.6 MB bf16 (gemm12 self-term)
#define OFF_XQ       (47ull << 20)  // 12.8 MB + zero row (fp8, N+1 rows)
#define OFF_AGGB     (61ull << 20)  // 25.6 MB bf16
#define OFF_T2A      (87ull << 20)  // 4.0 MB + zero row (dims 0-19, 40B rows)
#define OFF_T2B      (91ull << 20)  // 4.0 MB + zero row (dims 20-39)

static __device__ __forceinline__ unsigned short f2b(float f) {
    unsigned int u = __float_as_uint(f);
    u += 0x7fffu + ((u >> 16) & 1u);   // round-to-nearest-even
    return (unsigned short)(u >> 16);
}
static __device__ __forceinline__ float blo(unsigned int v) { return __uint_as_float(v << 16); }
static __device__ __forceinline__ float bhi(unsigned int v) { return __uint_as_float(v & 0xffff0000u); }

// ------------------------------------------------- CSR via counting sort

__global__ __launch_bounds__(256) void hist_local(
    const int* __restrict__ dst, int* __restrict__ hist, int E, int nbins) {
    __shared__ int h[1024];
    int b = blockIdx.x, t = threadIdx.x;
    for (int i = t; i < nbins; i += 256) h[i] = 0;
    __syncthreads();
    int chunk = (E + NB - 1) / NB;
    int base = b * chunk;
    int lim = min(base + chunk, E);
    for (int e = base + t; e < lim; e += 256)
        atomicAdd(&h[dst[e] >> BIN_SHIFT], 1);
    __syncthreads();
    for (int i = t; i < nbins; i += 256)
        hist[i * NB + b] = h[i];
}

__global__ void scan1(const int* __restrict__ in, int* __restrict__ tmp,
                      int* __restrict__ bsums, int M) {
    __shared__ int s[256];
    int t = threadIdx.x;
    int i = blockIdx.x * 256 + t;
    int v = (i < M) ? in[i] : 0;
    s[t] = v;
    __syncthreads();
    for (int off = 1; off < 256; off <<= 1) {
        int u = (t >= off) ? s[t - off] : 0;
        __syncthreads();
        s[t] += u;
        __syncthreads();
    }
    if (i < M) tmp[i] = s[t] - v;
    if (t == 255) bsums[blockIdx.x] = s[t];
}

__global__ void scan2(const int* __restrict__ bsums, int* __restrict__ boffs, int nb) {
    __shared__ int s[1024];
    int t = threadIdx.x;
    int v = (t < nb) ? bsums[t] : 0;
    s[t] = v;
    __syncthreads();
    for (int off = 1; off < 1024; off <<= 1) {
        int u = (t >= off) ? s[t - off] : 0;
        __syncthreads();
        s[t] += u;
        __syncthreads();
    }
    if (t < nb) boffs[t] = s[t] - v;
}

__global__ __launch_bounds__(256) void scatter_det(
    const int* __restrict__ src, const int* __restrict__ dst,
    const int* __restrict__ tmp, const int* __restrict__ boffs,
    unsigned int* __restrict__ packed, int E, int nbins) {
    __shared__ int cur[1024];
    int b = blockIdx.x, t = threadIdx.x;
    for (int i = t; i < nbins; i += 256) cur[i] = tmp[i * NB + b] + boffs[i];
    __syncthreads();
    int chunk = (E + NB - 1) / NB;
    int base = b * chunk;
    int lim = min(base + chunk, E);
    for (int e = base + t; e < lim; e += 256) {
        int d = dst[e];
        int bin = d >> BIN_SHIFT;
        int pos = atomicAdd(&cur[bin], 1);   // LDS atomic
        packed[pos] = ((unsigned int)(d & (BIN_SIZE - 1)) << 20) | (unsigned int)src[e];
    }
}

__global__ __launch_bounds__(256) void bin_fill(
    const unsigned int* __restrict__ packed, const int* __restrict__ tmp,
    const int* __restrict__ boffs,
    int* __restrict__ row_start, int* __restrict__ csr_src, int N, int nbins, int E) {
    __shared__ int cnt[BIN_SIZE];
    __shared__ int pre[BIN_SIZE];
    __shared__ int ex[BIN_SIZE];
    int b = blockIdx.x;
    int t = threadIdx.x;
    int node0 = b << BIN_SHIFT;
    int beg = tmp[b * NB] + boffs[b];
    int end = (b + 1 < nbins) ? (tmp[(b + 1) * NB] + boffs[b + 1]) : E;

    if (t < BIN_SIZE) cnt[t] = 0;
    __syncthreads();
    for (int i = beg + t; i < end; i += 256)
        atomicAdd(&cnt[packed[i] >> 20], 1);
    __syncthreads();
    if (t < BIN_SIZE) pre[t] = cnt[t];
    __syncthreads();
    for (int off = 1; off < BIN_SIZE; off <<= 1) {
        int u = (t < BIN_SIZE && t >= off) ? pre[t - off] : 0;
        __syncthreads();
        if (t < BIN_SIZE) pre[t] += u;
        __syncthreads();
    }
    if (t < BIN_SIZE) {
        ex[t] = pre[t] - cnt[t];
        int node = node0 + t;
        if (node < N) row_start[node] = beg + ex[t];
        cnt[t] = 0;
    }
    if (b == nbins - 1 && t == 0) row_start[N] = E;
    __syncthreads();
    for (int i = beg + t; i < end; i += 256) {
        unsigned int p = packed[i];
        int dl = p >> 20;
        int s = p & 0xFFFFF;
        int ofs = atomicAdd(&cnt[dl], 1);
        csr_src[beg + ex[dl] + ofs] = s;
    }
}

// ------------------------------------------------------------- prep kernel
// blocks [0, castBlocks): x -> xb (bf16) + xq (fp8 e4m3), 16 dims/thread.
// next 128: W1t transpose; next 80: W2t; last 1: zero rows (xq/t2a/t2b @ N).

__global__ void cast_prep(const float* __restrict__ x,
                          const float* __restrict__ W1s, const float* __restrict__ W1n,
                          const float* __restrict__ W2s, const float* __restrict__ W2n,
                          unsigned short* __restrict__ xb, unsigned char* __restrict__ xq,
                          unsigned short* __restrict__ W1t, unsigned short* __restrict__ W2t,
                          unsigned short* __restrict__ t2a, unsigned short* __restrict__ t2b,
                          int n16, int castBlocks, int N) {
    int blk = blockIdx.x, t = threadIdx.x;
    if (blk < castBlocks) {
        int i = blk * 256 + t;
        if (i >= n16) return;
        const float4* p = (const float4*)x + (size_t)i * 4;
        float4 v0 = p[0], v1 = p[1], v2 = p[2], v3 = p[3];
        float f[16] = {v0.x, v0.y, v0.z, v0.w, v1.x, v1.y, v1.z, v1.w,
                       v2.x, v2.y, v2.z, v2.w, v3.x, v3.y, v3.z, v3.w};
        unsigned short ob[16];
#pragma unroll
        for (int k = 0; k < 16; k++) ob[k] = f2b(f[k]);
        *(float4*)(xb + (size_t)i * 16) = *(float4*)&ob[0];
        *(float4*)(xb + (size_t)i * 16 + 8) = *(float4*)&ob[8];
        unsigned int w[4];
#pragma unroll
        for (int k = 0; k < 4; k++) {
            int u = __builtin_amdgcn_cvt_pk_fp8_f32(f[4 * k + 0], f[4 * k + 1], 0, false);
            u = __builtin_amdgcn_cvt_pk_fp8_f32(f[4 * k + 2], f[4 * k + 3], u, true);
            w[k] = (unsigned int)u;
        }
        *(uint4*)(xq + (size_t)i * 16) = *(uint4*)w;
    } else if (blk < castBlocks + 128) {
        int c = blk - castBlocks;
        float v = (t < 128) ? W1s[(size_t)t * 128 + c] : W1n[(size_t)(t - 128) * 128 + c];
        W1t[(size_t)c * 256 + t] = f2b(v);
    } else if (blk < castBlocks + 208) {
        if (t < 128) {
            int c = blk - castBlocks - 128;
            float v = (c < 40) ? W2s[(size_t)t * 40 + c] : W2n[(size_t)t * 40 + (c - 40)];
            W2t[(size_t)c * 128 + t] = f2b(v);
        }
    } else {
        // zero rows at index N (xq: 128B; t2a/t2b: 40B each)
        if (t < 32) ((unsigned int*)(xq + (size_t)N * 128))[t] = 0u;
        else if (t < 42) ((unsigned int*)((char*)t2a + (size_t)N * 40))[t - 32] = 0u;
        else if (t < 52) ((unsigned int*)((char*)t2b + (size_t)N * 40))[t - 42] = 0u;
    }
}

// ------------------------------------------------------- aggregation kernels

// One wave per node over fp8 rows (128 B). Quarter q handles edges e+4q+k
// (k=0..3); lane-in-quarter l owns dims [8l, 8l+8) via uint2. Out-of-range
// slots clamp to zero row N -> every iteration issues 4 gathers/lane.
__global__ void agg_mean_fp8(const unsigned char* __restrict__ xq,
                             const int* __restrict__ row_start,
                             const int* __restrict__ csr_src,
                             unsigned short* __restrict__ aggb, int N) {
    int wave = (blockIdx.x * blockDim.x + threadIdx.x) >> 6;
    int lane = threadIdx.x & 63;
    if (wave >= N) return;
    int q = lane >> 4;
    int l = lane & 15;
    int beg = row_start[wave], end = row_start[wave + 1];
    const char* xbase = (const char*)xq;
    unsigned loff = (unsigned)l << 3;

    float a[8];
#pragma unroll
    for (int k = 0; k < 8; k++) a[k] = 0.f;

    for (int e = beg; e < end; e += 16) {
        int eq = e + 4 * q;
        int s[4];
#pragma unroll
        for (int k = 0; k < 4; k++) {
            int ee = eq + k;
            int idx = csr_src[min(ee, end - 1)];
            s[k] = (ee < end) ? idx : N;          // N = zero row
        }
#pragma unroll
        for (int k = 0; k < 4; k++) {
            uint2 v = *(const uint2*)(xbase + (((unsigned)s[k] << 7) + loff));
            f32x2 p0 = __builtin_amdgcn_cvt_pk_f32_fp8(v.x, false);
            f32x2 p1 = __builtin_amdgcn_cvt_pk_f32_fp8(v.x, true);
            f32x2 p2 = __builtin_amdgcn_cvt_pk_f32_fp8(v.y, false);
            f32x2 p3 = __builtin_amdgcn_cvt_pk_f32_fp8(v.y, true);
            a[0] += p0.x; a[1] += p0.y; a[2] += p1.x; a[3] += p1.y;
            a[4] += p2.x; a[5] += p2.y; a[6] += p3.x; a[7] += p3.y;
        }
    }

#pragma unroll
    for (int k = 0; k < 8; k++) {
        a[k] += __shfl_xor(a[k], 16);
        a[k] += __shfl_xor(a[k], 32);
    }
    if (q == 0) {
        float inv = 1.0f / fmaxf((float)(end - beg), 1.0f);
        unsigned int ow[4];
#pragma unroll
        for (int k = 0; k < 4; k++)
            ow[k] = (unsigned int)f2b(a[2 * k] * inv) |
                    ((unsigned int)f2b(a[2 * k + 1] * inv) << 16);
        *(uint4*)((char*)aggb + (((unsigned)wave << 8) + ((unsigned)l << 4))) = *(uint4*)ow;
    }
}

// Layer-2 aggregation, dim-split for per-XCD L2 residency.
// Grid = 2 * ceil(N/4) blocks swizzled so blockIdx%8 in {0..3} -> half 0
// (table t2a, dims 0-19) and {4..7} -> half 1 (t2b, dims 20-39). Each 4.0MB
// table fits one XCD's L2. Wave = one node+half; quarter q handles edges
// e+4q+k; lanes l<10 gather one dword (2 bf16 dims) at row*40 + 4l. Zero row
// at N keeps the loop fully predicated. csr/out use nontemporal hints so the
// streams don't evict the resident table.
__global__ void agg2_split(const unsigned short* __restrict__ t2a,
                           const unsigned short* __restrict__ t2b,
                           const int* __restrict__ row_start,
                           const int* __restrict__ csr_src, const float* __restrict__ b2,
                           float* __restrict__ out, int N) {
    int bid = blockIdx.x;
    int h = (bid >> 2) & 1;                        // XCD group selects the table
    int nb = ((bid >> 3) << 2) | (bid & 3);        // node-block within half
    int node = nb * 4 + (threadIdx.x >> 6);
    if (node >= N) return;
    int lane = threadIdx.x & 63;
    int q = lane >> 4;
    int l = lane & 15;
    int beg = row_start[node], end = row_start[node + 1];
    const char* tb = h ? (const char*)t2b : (const char*)t2a;
    bool active = (l < 10);
    unsigned loff = (unsigned)l << 2;

    float a0 = 0.f, a1 = 0.f;

    for (int e = beg; e < end; e += 16) {
        int eq = e + 4 * q;
        int s[4];
#pragma unroll
        for (int k = 0; k < 4; k++) {
            int ee = eq + k;
            int idx = __builtin_nontemporal_load(csr_src + min(ee, end - 1));
            s[k] = (ee < end) ? idx : N;          // N = zero row
        }
        if (active) {
#pragma unroll
            for (int k = 0; k < 4; k++) {
                unsigned int v = *(const unsigned int*)(tb + ((unsigned)s[k] * 40u + loff));
                a0 += blo(v); a1 += bhi(v);
            }
        }
    }

    a0 += __shfl_xor(a0, 16); a0 += __shfl_xor(a0, 32);
    a1 += __shfl_xor(a1, 16); a1 += __shfl_xor(a1, 32);
    if (q == 0 && active) {
        float inv = 1.0f / fmaxf((float)(end - beg), 1.0f);
        const float* bp = b2 + h * 20 + l * 2;
        f32x2* op = (f32x2*)((char*)out + ((size_t)node * 160u + (unsigned)h * 80u + ((unsigned)l << 3)));
        f32x2 cur = __builtin_nontemporal_load(op);
        f32x2 nv;
        nv.x = cur.x + a0 * inv + bp[0];
        nv.y = cur.y + a1 * inv + bp[1];
        __builtin_nontemporal_store(nv, op);
    }
}

// --------------------------------------------------------------- fused GEMM
// Phase 1: h1 = relu([xb|aggb] @ W1cat + b1) into LDS (128x136-stride bf16).
// Phase 2: [out_self | t2a|t2b] = h1_tile @ W2cat (W2t in LDS, loaded once).

__global__ __launch_bounds__(256) void gemm12_mfma(
    const unsigned short* __restrict__ xb, const unsigned short* __restrict__ aggb,
    const unsigned short* __restrict__ W1t, const unsigned short* __restrict__ W2t,
    const float* __restrict__ b1, float* __restrict__ out,
    unsigned short* __restrict__ t2a, unsigned short* __restrict__ t2b, int N) {

    __shared__ unsigned short As[128 * 40];
    __shared__ unsigned short Bs[128 * 40];
    __shared__ unsigned short Hs[128 * 136];   // h1 tile, +8 pad
    __shared__ unsigned short B2[80 * 136];    // W2t resident

    int tid = threadIdx.x;
    int wave = tid >> 6, lane = tid & 63;
    int row0 = blockIdx.x * 128;
    int m = lane & 15, quad = lane >> 4;

    for (int idx = tid; idx < 1280; idx += 256) {
        int r = idx >> 4, seg = idx & 15;
        *(float4*)&B2[r * 136 + seg * 8] = *(const float4*)(W2t + (size_t)r * 128 + seg * 8);
    }

    f32x4 acc[2][8];
#pragma unroll
    for (int i = 0; i < 2; i++)
#pragma unroll
        for (int j = 0; j < 8; j++) acc[i][j] = (f32x4){0.f, 0.f, 0.f, 0.f};

    for (int k0 = 0; k0 < 256; k0 += 32) {
        __syncthreads();
        {
            int r = tid >> 1, kk = (tid & 1) * 16;
            int row = row0 + r;
            float4 v0 = make_float4(0, 0, 0, 0), v1 = v0;
            if (row < N) {
                const unsigned short* s = (k0 < 128)
                    ? (xb + (size_t)row * 128 + k0 + kk)
                    : (aggb + (size_t)row * 128 + (k0 - 128) + kk);
                const float4* p = (const float4*)s;
                v0 = p[0]; v1 = p[1];
            }
            *(float4*)&As[r * 40 + kk] = v0;
            *(float4*)&As[r * 40 + kk + 8] = v1;
            const float4* q2 = (const float4*)(W1t + (size_t)r * 256 + k0 + kk);
            float4 w0 = q2[0], w1 = q2[1];
            *(float4*)&Bs[r * 40 + kk] = w0;
            *(float4*)&Bs[r * 40 + kk + 8] = w1;
        }
        __syncthreads();

        bf16x8 af0 = *(bf16x8*)&As[(wave * 32 + m) * 40 + quad * 8];
        bf16x8 af1 = *(bf16x8*)&As[(wave * 32 + 16 + m) * 40 + quad * 8];
#pragma unroll
        for (int j = 0; j < 8; j++) {
            bf16x8 bfg = *(bf16x8*)&Bs[(j * 16 + m) * 40 + quad * 8];
            acc[0][j] = __builtin_amdgcn_mfma_f32_16x16x32_bf16(af0, bfg, acc[0][j], 0, 0, 0);
            acc[1][j] = __builtin_amdgcn_mfma_f32_16x16x32_bf16(af1, bfg, acc[1][j], 0, 0, 0);
        }
    }

#pragma unroll
    for (int j = 0; j < 8; j++) {
        int col = j * 16 + m;
        float bias = b1[col];
#pragma unroll
        for (int i = 0; i < 2; i++) {
#pragma unroll
            for (int r = 0; r < 4; r++) {
                int rl = wave * 32 + i * 16 + quad * 4 + r;
                Hs[rl * 136 + col] = f2b(fmaxf(acc[i][j][r] + bias, 0.f));
            }
        }
    }
    __syncthreads();

    f32x4 acc2[2][5];
#pragma unroll
    for (int i = 0; i < 2; i++)
#pragma unroll
        for (int j = 0; j < 5; j++) acc2[i][j] = (f32x4){0.f, 0.f, 0.f, 0.f};

#pragma unroll
    for (int k0 = 0; k0 < 128; k0 += 32) {
        bf16x8 af0 = *(bf16x8*)&Hs[(wave * 32 + m) * 136 + k0 + quad * 8];
        bf16x8 af1 = *(bf16x8*)&Hs[(wave * 32 + 16 + m) * 136 + k0 + quad * 8];
#pragma unroll
        for (int j = 0; j < 5; j++) {
            bf16x8 bfg = *(bf16x8*)&B2[(j * 16 + m) * 136 + k0 + quad * 8];
            acc2[0][j] = __builtin_amdgcn_mfma_f32_16x16x32_bf16(af0, bfg, acc2[0][j], 0, 0, 0);
            acc2[1][j] = __builtin_amdgcn_mfma_f32_16x16x32_bf16(af1, bfg, acc2[1][j], 0, 0, 0);
        }
    }

#pragma unroll
    for (int j = 0; j < 5; j++) {
        int col = j * 16 + m;
#pragma unroll
        for (int i = 0; i < 2; i++) {
#pragma unroll
            for (int r = 0; r < 4; r++) {
                int row = row0 + wave * 32 + i * 16 + quad * 4 + r;
                if (row < N) {
                    float v = acc2[i][j][r];
                    if (col < 40) {
                        out[(size_t)row * 40 + col] = v;
                    } else {
                        int td = col - 40;
                        unsigned short hv = f2b(v);
                        if (td < 20) t2a[(size_t)row * 20 + td] = hv;
                        else         t2b[(size_t)row * 20 + (td - 20)] = hv;
                    }
                }
            }
        }
    }
}

// ------------------------------------------------------------------ launch

extern "C" void kernel_launch(void* const* d_in, const int* in_sizes, int n_in,
                              void* d_out, int out_size, void* d_ws, size_t ws_size,
                              hipStream_t stream) {
    const float* x   = (const float*)d_in[0];
    const int*   src = (const int*)d_in[1];
    const int*   dst = (const int*)d_in[2];
    const float* W1s = (const float*)d_in[3];
    const float* W1n = (const float*)d_in[4];
    const float* b1  = (const float*)d_in[5];
    const float* W2s = (const float*)d_in[6];
    const float* W2n = (const float*)d_in[7];
    const float* b2  = (const float*)d_in[8];
    float* out = (float*)d_out;

    int N = in_sizes[0] / 128;
    int E = in_sizes[1];
    int nbins = (N + BIN_SIZE - 1) / BIN_SIZE;   // 782 for N=100000
    int M = nbins * NB;

    char* ws = (char*)d_ws;
    int*            row_start  = (int*)(ws + OFF_ROWSTART);
    int*            hist       = (int*)(ws + OFF_HIST);
    int*            scanned    = (int*)(ws + OFF_SCAN);
    int*            bsums      = (int*)(ws + OFF_BSUMS);
    int*            boffs      = (int*)(ws + OFF_BOFFS);
    unsigned int*   packed     = (unsigned int*)(ws + OFF_PACKED);
    int*            csr_src    = (int*)(ws + OFF_CSR);
    unsigned short* W1t        = (unsigned short*)(ws + OFF_W1T);
    unsigned short* W2t        = (unsigned short*)(ws + OFF_W2T);
    unsigned short* xb         = (unsigned short*)(ws + OFF_XB);
    unsigned char*  xq         = (unsigned char*)(ws + OFF_XQ);
    unsigned short* aggb       = (unsigned short*)(ws + OFF_AGGB);
    unsigned short* t2a        = (unsigned short*)(ws + OFF_T2A);
    unsigned short* t2b        = (unsigned short*)(ws + OFF_T2B);

    int scanBlocks = (M + 255) / 256;            // == nbins

    hist_local<<<NB, 256, 0, stream>>>(dst, hist, E, nbins);
    scan1<<<scanBlocks, 256, 0, stream>>>(hist, scanned, bsums, M);
    scan2<<<1, 1024, 0, stream>>>(bsums, boffs, scanBlocks);
    scatter_det<<<NB, 256, 0, stream>>>(src, dst, scanned, boffs, packed, E, nbins);
    bin_fill<<<nbins, 256, 0, stream>>>(packed, scanned, boffs, row_start, csr_src, N, nbins, E);

    int n16 = N * 128 / 16;
    int castBlocks = (n16 + 255) / 256;
    cast_prep<<<castBlocks + 128 + 80 + 1, 256, 0, stream>>>(
        x, W1s, W1n, W2s, W2n, xb, xq, W1t, W2t, t2a, t2b, n16, castBlocks, N);

    int aggBlocks = (N * 64 + 255) / 256;
    agg_mean_fp8<<<aggBlocks, 256, 0, stream>>>(xq, row_start, csr_src, aggb, N);
    gemm12_mfma<<<(N + 127) / 128, 256, 0, stream>>>(xb, aggb, W1t, W2t, b1, out, t2a, t2b, N);

    int B0 = (N + 3) / 4;
    int blocks2 = ((2 * B0 + 7) / 8) * 8;        // 50000 for N=100000
    agg2_split<<<blocks2, 256, 0, stream>>>(t2a, t2b, row_start, csr_src, b2, out, N);
}